// Round 2
// baseline (114.105 us; speedup 1.0000x reference)
//
#include <hip/hip_runtime.h>

typedef float f32x4 __attribute__((ext_vector_type(4)));

// Single fused kernel: per-block uniform sincos (2 scalar loads + 2 sincosf,
// amortized over 32 float4 elements/thread), grid-stride within batch,
// non-temporal streaming loads/stores (data is touch-once, 512 MiB total
// round trip > 256 MiB L3 -> don't pollute caches).
//
// Grid: y = batch (16), x = 128 blocks x 256 threads -> 2048 WGs total
// = 8192 waves = exactly 32 waves/CU on 256 CUs.
__global__ void __launch_bounds__(256) rot_apply_fused(
        const f32x4* __restrict__ in,
        f32x4* __restrict__ out,
        const float* __restrict__ theta,
        const float* __restrict__ phi,
        int per4) {
    const int b = blockIdx.y;

    // Wave-uniform angle setup; tiny cost, hidden under first loads.
    float st, ct, sp, cp;
    sincosf(theta[b], &st, &ct);
    sincosf(phi[b],   &sp, &cp);

    const long long base = (long long)b * per4;
    const int stride = blockDim.x * gridDim.x;

    for (int i = blockIdx.x * blockDim.x + threadIdx.x; i < per4; i += stride) {
        f32x4 v = __builtin_nontemporal_load(&in[base + i]);
        f32x4 o;
        o.x =  v.x * ct + v.y * st;
        o.y = -v.x * st + v.y * ct;
        o.z =  v.z * cp + v.w * sp;
        o.w = -v.z * sp + v.w * cp;
        __builtin_nontemporal_store(o, &out[base + i]);
    }
}

extern "C" void kernel_launch(void* const* d_in, const int* in_sizes, int n_in,
                              void* d_out, int out_size, void* d_ws, size_t ws_size,
                              hipStream_t stream) {
    const float* emb   = (const float*)d_in[0];
    const float* theta = (const float*)d_in[1];
    const float* phi   = (const float*)d_in[2];
    float* out = (float*)d_out;

    int B = in_sizes[1];                       // theta has B elements
    long long total = (long long)in_sizes[0];  // B*N*D
    long long per_batch = total / B;           // N*D
    int per4 = (int)(per_batch / 4);           // float4 blocks per batch

    const int threads = 256;
    // ~2048 total workgroups: 32 waves/CU exact fill at low VGPR use.
    int blocksX = 2048 / (B > 0 ? B : 1);
    if (blocksX < 1) blocksX = 1;
    int maxBlocksX = (per4 + threads - 1) / threads;
    if (blocksX > maxBlocksX) blocksX = maxBlocksX;

    dim3 grid(blocksX, B);
    rot_apply_fused<<<grid, threads, 0, stream>>>(
        (const f32x4*)emb, (f32x4*)out, theta, phi, per4);
}

// Round 3
// 97.761 us; speedup vs baseline: 1.1672x; 1.1672x over previous
//
#include <hip/hip_runtime.h>

typedef float f32x4 __attribute__((ext_vector_type(4)));

// One fused kernel. Per-block wave-uniform sincos (2 scalar loads + 2 sincosf,
// amortized over 512 float4s per block). Each thread handles TWO independent
// float4 elements (both loads issued before either use -> 2x MLP per wave).
// No grid-stride loop, no nontemporal hints (NT stores defeat L2 write
// coalescing on CDNA and regressed round 2).
//
// Grid: y = batch (16), x = per4 / 512 = 2048 blocks of 256 threads.
__global__ void __launch_bounds__(256) rot_apply2(
        const f32x4* __restrict__ in,
        f32x4* __restrict__ out,
        const float* __restrict__ theta,
        const float* __restrict__ phi,
        int per4) {
    const int b = blockIdx.y;

    float st, ct, sp, cp;
    sincosf(theta[b], &st, &ct);
    sincosf(phi[b],   &sp, &cp);

    const long long base = (long long)b * per4;
    const int i0 = blockIdx.x * (blockDim.x * 2) + threadIdx.x;
    const int i1 = i0 + blockDim.x;

    // Issue both loads before any use: compiler emits two global_load_dwordx4
    // back-to-back, single s_waitcnt covers both.
    f32x4 v0, v1;
    bool ok0 = i0 < per4, ok1 = i1 < per4;
    if (ok0) v0 = in[base + i0];
    if (ok1) v1 = in[base + i1];

    if (ok0) {
        f32x4 o;
        o.x =  v0.x * ct + v0.y * st;
        o.y = -v0.x * st + v0.y * ct;
        o.z =  v0.z * cp + v0.w * sp;
        o.w = -v0.z * sp + v0.w * cp;
        out[base + i0] = o;
    }
    if (ok1) {
        f32x4 o;
        o.x =  v1.x * ct + v1.y * st;
        o.y = -v1.x * st + v1.y * ct;
        o.z =  v1.z * cp + v1.w * sp;
        o.w = -v1.z * sp + v1.w * cp;
        out[base + i1] = o;
    }
}

extern "C" void kernel_launch(void* const* d_in, const int* in_sizes, int n_in,
                              void* d_out, int out_size, void* d_ws, size_t ws_size,
                              hipStream_t stream) {
    const float* emb   = (const float*)d_in[0];
    const float* theta = (const float*)d_in[1];
    const float* phi   = (const float*)d_in[2];
    float* out = (float*)d_out;

    int B = in_sizes[1];                       // theta has B elements
    long long total = (long long)in_sizes[0];  // B*N*D
    long long per_batch = total / B;           // N*D
    int per4 = (int)(per_batch / 4);           // float4 blocks per batch

    const int threads = 256;
    const int per_block = threads * 2;         // 2 float4 per thread
    int blocksX = (per4 + per_block - 1) / per_block;

    dim3 grid(blocksX, B);
    rot_apply2<<<grid, threads, 0, stream>>>(
        (const f32x4*)emb, (f32x4*)out, theta, phi, per4);
}

// Round 4
// 82.723 us; speedup vs baseline: 1.3794x; 1.1818x over previous
//
#include <hip/hip_runtime.h>

typedef float f32x4 __attribute__((ext_vector_type(4)));

// Round-3 structure exactly, ONE change: non-temporal LOADS (reads are
// touch-once, 256 MiB input streams through the 256 MiB L3 and would
// otherwise thrash the write stream's cache lines). Stores stay normal
// (NT stores regressed round 2 — L2 write coalescing matters).
//
// Grid: y = batch (16), x = per4 / 512 = 2048 blocks of 256 threads.
__global__ void __launch_bounds__(256) rot_apply2nt(
        const f32x4* __restrict__ in,
        f32x4* __restrict__ out,
        const float* __restrict__ theta,
        const float* __restrict__ phi,
        int per4) {
    const int b = blockIdx.y;

    float st, ct, sp, cp;
    sincosf(theta[b], &st, &ct);
    sincosf(phi[b],   &sp, &cp);

    const long long base = (long long)b * per4;
    const int i0 = blockIdx.x * (blockDim.x * 2) + threadIdx.x;
    const int i1 = i0 + blockDim.x;

    f32x4 v0, v1;
    bool ok0 = i0 < per4, ok1 = i1 < per4;
    if (ok0) v0 = __builtin_nontemporal_load(&in[base + i0]);
    if (ok1) v1 = __builtin_nontemporal_load(&in[base + i1]);

    if (ok0) {
        f32x4 o;
        o.x =  v0.x * ct + v0.y * st;
        o.y = -v0.x * st + v0.y * ct;
        o.z =  v0.z * cp + v0.w * sp;
        o.w = -v0.z * sp + v0.w * cp;
        out[base + i0] = o;
    }
    if (ok1) {
        f32x4 o;
        o.x =  v1.x * ct + v1.y * st;
        o.y = -v1.x * st + v1.y * ct;
        o.z =  v1.z * cp + v1.w * sp;
        o.w = -v1.z * sp + v1.w * cp;
        out[base + i1] = o;
    }
}

extern "C" void kernel_launch(void* const* d_in, const int* in_sizes, int n_in,
                              void* d_out, int out_size, void* d_ws, size_t ws_size,
                              hipStream_t stream) {
    const float* emb   = (const float*)d_in[0];
    const float* theta = (const float*)d_in[1];
    const float* phi   = (const float*)d_in[2];
    float* out = (float*)d_out;

    int B = in_sizes[1];                       // theta has B elements
    long long total = (long long)in_sizes[0];  // B*N*D
    long long per_batch = total / B;           // N*D
    int per4 = (int)(per_batch / 4);           // float4 blocks per batch

    const int threads = 256;
    const int per_block = threads * 2;         // 2 float4 per thread
    int blocksX = (per4 + per_block - 1) / per_block;

    dim3 grid(blocksX, B);
    rot_apply2nt<<<grid, threads, 0, stream>>>(
        (const f32x4*)emb, (f32x4*)out, theta, phi, per4);
}